// Round 2
// baseline (296.265 us; speedup 1.0000x reference)
//
#include <hip/hip_runtime.h>

#define VOCAB  32000
#define NSTATE 64
#define NLABEL 16
#define BATCH  512
#define MAXLEN 512

#define LOG2E 1.44269504088896340736f
#define LN2_D 0.69314718055994530942

#if defined(__has_builtin) && __has_builtin(__builtin_amdgcn_exp2f)
#define EXP2(x) __builtin_amdgcn_exp2f(x)
#else
#define EXP2(x) exp2f(x)
#endif
#if defined(__has_builtin) && __has_builtin(__builtin_amdgcn_logf)
#define LOG2(x) __builtin_amdgcn_logf(x)   // v_log_f32 = log2
#else
#define LOG2(x) log2f(x)
#endif

__device__ __forceinline__ float wave_max64(float x) {
#pragma unroll
  for (int off = 32; off > 0; off >>= 1) x = fmaxf(x, __shfl_xor(x, off, 64));
  return x;
}
__device__ __forceinline__ float wave_sum64(float x) {
#pragma unroll
  for (int off = 32; off > 0; off >>= 1) x += __shfl_xor(x, off, 64);
  return x;
}
__device__ __forceinline__ float bcast0(float x) {
  return __uint_as_float(__builtin_amdgcn_readfirstlane(__float_as_uint(x)));
}

// --- prep: emb2[w][s] = log2_softmax(emb[w]*log2e)  (denominator folded in) ---
__global__ void prep_emb_k(const float* __restrict__ emb, float* __restrict__ emb2) {
  const int w = blockIdx.x * 4 + (threadIdx.x >> 6);
  const int s = threadIdx.x & 63;
  const float v = emb[w * NSTATE + s] * LOG2E;
  const float m = wave_max64(v);
  const float ss = wave_sum64(EXP2(v - m));
  emb2[w * NSTATE + s] = v - m - LOG2(ss);
}

// --- prep: W = softmax(transition) rows; out2 = log2_softmax(output) rows ---
__global__ void prep_mats_k(const float* __restrict__ trans, const float* __restrict__ outp,
                            float* __restrict__ W, float* __restrict__ out2) {
  const int r = blockIdx.x, s = threadIdx.x;
  if (r < NSTATE) {
    const float v = trans[r * NSTATE + s] * LOG2E;
    const float m = wave_max64(v);
    const float ss = wave_sum64(EXP2(v - m));
    W[r * NSTATE + s] = EXP2(v - m - LOG2(ss));
  } else {
    const int l = r - NSTATE;
    const float v = outp[l * NSTATE + s] * LOG2E;
    const float m = wave_max64(v);
    const float ss = wave_sum64(EXP2(v - m));
    out2[l * NSTATE + s] = v - m - LOG2(ss);
  }
}

// --- main: one wave per batch row, lane s owns state s ---
template <bool PRE>
__global__ __launch_bounds__(64) void iohmm_fwd(
    const int* __restrict__ sents, const int* __restrict__ length,
    const float* __restrict__ emb, const float* __restrict__ trans,
    const float* __restrict__ outp, const float* __restrict__ emb2,
    const float* __restrict__ W, const float* __restrict__ out2,
    float* __restrict__ score) {
  const int b = blockIdx.x;
  const int s = threadIdx.x;
  __shared__ __align__(16) float p_lds[2][NSTATE];
  __shared__ __align__(16) int s_ids[MAXLEN];

  // stage all word ids for this row into LDS (2 KB): 2 x int4 per lane
  {
    const int4* s4 = reinterpret_cast<const int4*>(sents + b * MAXLEN);
    int4 c0 = s4[s];
    int4 c1 = s4[64 + s];
    reinterpret_cast<int4*>(s_ids)[s] = c0;
    reinterpret_cast<int4*>(s_ids)[64 + s] = c1;
  }

  // W row s in registers (64 VGPRs)
  float wreg[NSTATE];
  if (PRE) {
#pragma unroll
    for (int j = 0; j < 16; ++j) {
      const float4 q = *reinterpret_cast<const float4*>(W + s * NSTATE + 4 * j);
      wreg[4 * j + 0] = q.x; wreg[4 * j + 1] = q.y;
      wreg[4 * j + 2] = q.z; wreg[4 * j + 3] = q.w;
    }
  } else {
#pragma unroll
    for (int j = 0; j < 16; ++j) {
      const float4 q = *reinterpret_cast<const float4*>(trans + s * NSTATE + 4 * j);
      wreg[4 * j + 0] = q.x * LOG2E; wreg[4 * j + 1] = q.y * LOG2E;
      wreg[4 * j + 2] = q.z * LOG2E; wreg[4 * j + 3] = q.w * LOG2E;
    }
    float m = -1e30f;
#pragma unroll
    for (int j = 0; j < NSTATE; ++j) m = fmaxf(m, wreg[j]);
    float ss = 0.f;
#pragma unroll
    for (int j = 0; j < NSTATE; ++j) ss += EXP2(wreg[j] - m);
    const float d = m + LOG2(ss);
#pragma unroll
    for (int j = 0; j < NSTATE; ++j) wreg[j] = EXP2(wreg[j] - d);
  }

  const int len = length[b];
  __syncthreads();  // s_ids visible

  // f0 = emission[0] (log2 domain, relative representation; MU holds the shift)
  const int w0 = s_ids[0];
  float f;
  if (PRE) {
    f = emb2[w0 * NSTATE + s];
  } else {
    const float v = emb[w0 * NSTATE + s] * LOG2E;
    const float dm = wave_max64(v);
    const float dsum = wave_sum64(EXP2(v - dm));
    f = v - dm - LOG2(dsum);
  }
  double MU = 0.0;

  // software pipeline: e_cur = raw emission for step t; id_pref = word id for step t+1
  int id1 = s_ids[1];
  float e_cur = PRE ? emb2[id1 * NSTATE + s] : emb[id1 * NSTATE + s] * LOG2E;
  int id_pref = s_ids[2];

  for (int t = 1; t < len; ++t) {
    // issue next-iteration prefetches first (independent of this step's compute)
    const float e_nxt = PRE ? emb2[id_pref * NSTATE + s]
                            : emb[id_pref * NSTATE + s] * LOG2E;   // emission(t+1)
    const int tpp = t + 2;
    const int id_nxt = s_ids[tpp < MAXLEN ? tpp : MAXLEN - 1];      // id(t+2)

    // wave-uniform shift: lane0's f (spread across lanes bounded by ~3 bits)
    const float shift = bcast0(f);
    const float p = EXP2(f - shift);
    float* pb = p_lds[t & 1];
    pb[s] = p;
    __syncthreads();  // write visible (waitcnt + barrier); double-buffer kills WAR

    float a0 = 0.f, a1 = 0.f, a2 = 0.f, a3 = 0.f;
    float a4 = 0.f, a5 = 0.f, a6 = 0.f, a7 = 0.f;
#pragma unroll
    for (int j = 0; j < 8; ++j) {
      const float4 q0 = *reinterpret_cast<const float4*>(pb + 8 * j);
      const float4 q1 = *reinterpret_cast<const float4*>(pb + 8 * j + 4);
      a0 = fmaf(wreg[8 * j + 0], q0.x, a0);
      a1 = fmaf(wreg[8 * j + 1], q0.y, a1);
      a2 = fmaf(wreg[8 * j + 2], q0.z, a2);
      a3 = fmaf(wreg[8 * j + 3], q0.w, a3);
      a4 = fmaf(wreg[8 * j + 4], q1.x, a4);
      a5 = fmaf(wreg[8 * j + 5], q1.y, a5);
      a6 = fmaf(wreg[8 * j + 6], q1.z, a6);
      a7 = fmaf(wreg[8 * j + 7], q1.w, a7);
    }
    const float sum = ((a0 + a4) + (a1 + a5)) + ((a2 + a6) + (a3 + a7));

    float e;
    if (PRE) {
      e = e_cur;
    } else {
      const float dm = wave_max64(e_cur);
      const float dsum = wave_sum64(EXP2(e_cur - dm));
      e = e_cur - dm - LOG2(dsum);
    }
    f = LOG2(sum) + e;     // stays O(+-10): full fp32 precision
    MU += (double)shift;   // large shift accumulates exactly in f64

    e_cur = e_nxt;
    id_pref = id_nxt;
  }

  // epilogue: score[b][l] = lse_s(out_log[l][s] + hidden[s]) / log2e
  for (int l = 0; l < NLABEL; ++l) {
    float y;
    if (PRE) {
      y = out2[l * NSTATE + s] + f;
    } else {
      const float v = outp[l * NSTATE + s] * LOG2E;
      const float lm = wave_max64(v);
      const float lsum = wave_sum64(EXP2(v - lm));
      y = v - lm - LOG2(lsum) + f;
    }
    const float m = wave_max64(y);
    const float ssum = wave_sum64(EXP2(y - m));
    if (s == 0) {
      const double sc = MU + (double)m + (double)LOG2(ssum);
      score[b * NLABEL + l] = (float)(sc * LN2_D);
    }
  }
}

extern "C" void kernel_launch(void* const* d_in, const int* in_sizes, int n_in,
                              void* d_out, int out_size, void* d_ws, size_t ws_size,
                              hipStream_t stream) {
  const int* sents = (const int*)d_in[0];
  const int* length = (const int*)d_in[1];
  const float* emb = (const float*)d_in[2];
  const float* trans = (const float*)d_in[3];
  const float* outp = (const float*)d_in[4];
  float* score = (float*)d_out;

  const size_t emb2_bytes = (size_t)VOCAB * NSTATE * sizeof(float);
  const size_t W_off = emb2_bytes;
  const size_t out2_off = W_off + NSTATE * NSTATE * sizeof(float);
  const size_t need = out2_off + NLABEL * NSTATE * sizeof(float);

  if (ws_size >= need) {
    float* emb2 = (float*)d_ws;
    float* W = (float*)((char*)d_ws + W_off);
    float* out2 = (float*)((char*)d_ws + out2_off);
    prep_emb_k<<<VOCAB / 4, 256, 0, stream>>>(emb, emb2);
    prep_mats_k<<<NSTATE + NLABEL, 64, 0, stream>>>(trans, outp, W, out2);
    iohmm_fwd<true><<<BATCH, 64, 0, stream>>>(sents, length, emb, trans, outp,
                                              emb2, W, out2, score);
  } else {
    iohmm_fwd<false><<<BATCH, 64, 0, stream>>>(sents, length, emb, trans, outp,
                                               nullptr, nullptr, nullptr, score);
  }
}

// Round 3
// 261.396 us; speedup vs baseline: 1.1334x; 1.1334x over previous
//
#include <hip/hip_runtime.h>
#include <stdint.h>

#define VOCAB  32000
#define NSTATE 64
#define NLABEL 16
#define BATCH  512
#define MAXLEN 512

#define LOG2E 1.44269504088896340736f
#define LN2_D 0.69314718055994530942

typedef float v2f __attribute__((ext_vector_type(2)));

#if defined(__has_builtin) && __has_builtin(__builtin_amdgcn_exp2f)
#define EXP2(x) __builtin_amdgcn_exp2f(x)
#else
#define EXP2(x) exp2f(x)
#endif
#if defined(__has_builtin) && __has_builtin(__builtin_amdgcn_logf)
#define LOG2(x) __builtin_amdgcn_logf(x)   // v_log_f32 = log2
#else
#define LOG2(x) log2f(x)
#endif

__device__ __forceinline__ float wave_max64(float x) {
#pragma unroll
  for (int off = 32; off > 0; off >>= 1) x = fmaxf(x, __shfl_xor(x, off, 64));
  return x;
}
__device__ __forceinline__ float wave_sum64(float x) {
#pragma unroll
  for (int off = 32; off > 0; off >>= 1) x += __shfl_xor(x, off, 64);
  return x;
}
__device__ __forceinline__ float bcast0(float x) {
  return __uint_as_float(__builtin_amdgcn_readfirstlane(__float_as_uint(x)));
}

// --- prep: emb2[w][s] = log2_softmax(emb[w]*log2e)  (denominator folded in) ---
__global__ void prep_emb_k(const float* __restrict__ emb, float* __restrict__ emb2) {
  const int w = blockIdx.x * 4 + (threadIdx.x >> 6);
  const int s = threadIdx.x & 63;
  const float v = emb[w * NSTATE + s] * LOG2E;
  const float m = wave_max64(v);
  const float ss = wave_sum64(EXP2(v - m));
  emb2[w * NSTATE + s] = v - m - LOG2(ss);
}

// --- prep: W = softmax(transition) rows; out2 = log2_softmax(output) rows ---
__global__ void prep_mats_k(const float* __restrict__ trans, const float* __restrict__ outp,
                            float* __restrict__ W, float* __restrict__ out2) {
  const int r = blockIdx.x, s = threadIdx.x;
  if (r < NSTATE) {
    const float v = trans[r * NSTATE + s] * LOG2E;
    const float m = wave_max64(v);
    const float ss = wave_sum64(EXP2(v - m));
    W[r * NSTATE + s] = EXP2(v - m - LOG2(ss));
  } else {
    const int l = r - NSTATE;
    const float v = outp[l * NSTATE + s] * LOG2E;
    const float m = wave_max64(v);
    const float ss = wave_sum64(EXP2(v - m));
    out2[l * NSTATE + s] = v - m - LOG2(ss);
  }
}

// --- main: one wave per batch row, lane s owns state s ---
// Linear-domain recursion: p <- (W · p) * q_t,  q_t = 2^(e_t - bcast0(e_t)),
// MU accumulates bcast0(e_t) (f64) + exact power-of-two renorms (int).
template <bool PRE>
__global__ __launch_bounds__(64) void iohmm_fwd(
    const int* __restrict__ sents, const int* __restrict__ length,
    const float* __restrict__ emb, const float* __restrict__ trans,
    const float* __restrict__ outp, const float* __restrict__ emb2,
    const float* __restrict__ W, const float* __restrict__ out2,
    float* __restrict__ score) {
  const int b = blockIdx.x;
  const int s = threadIdx.x;
  __shared__ __align__(16) float p_lds[2][NSTATE];
  __shared__ __align__(16) int s_ids[MAXLEN];

  // stage all word ids for this row into LDS (2 KB): 2 x int4 per lane
  {
    const int4* s4 = reinterpret_cast<const int4*>(sents + b * MAXLEN);
    int4 c0 = s4[s];
    int4 c1 = s4[64 + s];
    reinterpret_cast<int4*>(s_ids)[s] = c0;
    reinterpret_cast<int4*>(s_ids)[64 + s] = c1;
  }

  // W row s in registers as 32 float2 (64 VGPRs)
  v2f w2[NSTATE / 2];
  if (PRE) {
#pragma unroll
    for (int j = 0; j < 16; ++j) {
      const float4 q = *reinterpret_cast<const float4*>(W + s * NSTATE + 4 * j);
      w2[2 * j + 0] = v2f{q.x, q.y};
      w2[2 * j + 1] = v2f{q.z, q.w};
    }
  } else {
    float wr[NSTATE];
#pragma unroll
    for (int j = 0; j < 16; ++j) {
      const float4 q = *reinterpret_cast<const float4*>(trans + s * NSTATE + 4 * j);
      wr[4 * j + 0] = q.x * LOG2E; wr[4 * j + 1] = q.y * LOG2E;
      wr[4 * j + 2] = q.z * LOG2E; wr[4 * j + 3] = q.w * LOG2E;
    }
    float m = -1e30f;
#pragma unroll
    for (int j = 0; j < NSTATE; ++j) m = fmaxf(m, wr[j]);
    float ss = 0.f;
#pragma unroll
    for (int j = 0; j < NSTATE; ++j) ss += EXP2(wr[j] - m);
    const float d = m + LOG2(ss);
#pragma unroll
    for (int j = 0; j < NSTATE / 2; ++j)
      w2[j] = v2f{EXP2(wr[2 * j] - d), EXP2(wr[2 * j + 1] - d)};
  }

  const int len = length[b];
  __syncthreads();  // one-time: s_ids visible (outside hot loop)

  // p0 from emission[0]
  const int w0 = s_ids[0];
  float e0;
  if (PRE) {
    e0 = emb2[w0 * NSTATE + s];
  } else {
    const float v = emb[w0 * NSTATE + s] * LOG2E;
    const float dm = wave_max64(v);
    const float dsum = wave_sum64(EXP2(v - dm));
    e0 = v - dm - LOG2(dsum);
  }
  const float se0 = bcast0(e0);
  float p = EXP2(e0 - se0);
  double MU = (double)se0;
  int MUi = 0;

  // software pipeline: e_r = raw emission row for step t (in flight), id_pref = id for t+1
  const int id1 = s_ids[1];
  float e_r = PRE ? emb2[id1 * NSTATE + s] : emb[id1 * NSTATE + s] * LOG2E;
  int id_pref = s_ids[2];

#pragma unroll 2
  for (int t = 1; t < len; ++t) {
    // chain head: publish p for this step
    float* pb = p_lds[t & 1];
    pb[s] = p;

    // issue next-iteration prefetches (ride across iterations; no barrier drain)
    const float e_nxt = PRE ? emb2[id_pref * NSTATE + s]
                            : emb[id_pref * NSTATE + s] * LOG2E;
    const int tpp = t + 2;
    const int id_nxt = s_ids[tpp < MAXLEN ? tpp : MAXLEN - 1];

    // off-chain: q for this step from prefetched emission (budget = 1 full iteration)
    float e;
    if (PRE) {
      e = e_r;
    } else {
      const float dm = wave_max64(e_r);
      const float dsum = wave_sum64(EXP2(e_r - dm));
      e = e_r - dm - LOG2(dsum);
    }
    const float se = bcast0(e);
    const float q = EXP2(e - se);

    // single-wave block: ds ops in order; wait only LDS counter (vmcnt rides on)
    asm volatile("s_waitcnt lgkmcnt(0)" ::: "memory");

    // dot: 32 packed fp32 FMAs, 8 v2f accumulators, broadcast b128 reads
    const float4* pb4 = reinterpret_cast<const float4*>(pb);
    v2f A0{0.f, 0.f}, A1 = A0, A2 = A0, A3 = A0, A4 = A0, A5 = A0, A6 = A0, A7 = A0;
#pragma unroll
    for (int j = 0; j < 4; ++j) {
      const float4 qa = pb4[4 * j + 0];
      const float4 qb = pb4[4 * j + 1];
      const float4 qc = pb4[4 * j + 2];
      const float4 qd = pb4[4 * j + 3];
      A0 = __builtin_elementwise_fma(w2[8 * j + 0], v2f{qa.x, qa.y}, A0);
      A1 = __builtin_elementwise_fma(w2[8 * j + 1], v2f{qa.z, qa.w}, A1);
      A2 = __builtin_elementwise_fma(w2[8 * j + 2], v2f{qb.x, qb.y}, A2);
      A3 = __builtin_elementwise_fma(w2[8 * j + 3], v2f{qb.z, qb.w}, A3);
      A4 = __builtin_elementwise_fma(w2[8 * j + 4], v2f{qc.x, qc.y}, A4);
      A5 = __builtin_elementwise_fma(w2[8 * j + 5], v2f{qc.z, qc.w}, A5);
      A6 = __builtin_elementwise_fma(w2[8 * j + 6], v2f{qd.x, qd.y}, A6);
      A7 = __builtin_elementwise_fma(w2[8 * j + 7], v2f{qd.z, qd.w}, A7);
    }
    const v2f S0 = A0 + A4, S1 = A1 + A5, S2 = A2 + A6, S3 = A3 + A7;
    const v2f T0 = S0 + S2, T1 = S1 + S3;
    const v2f U = T0 + T1;
    const float sum = U.x + U.y;

    p = sum * q;

    if ((t & 15) == 0) {  // exact power-of-two renorm (no rounding error)
      const uint32_t u = __builtin_amdgcn_readfirstlane(__float_as_uint(p));
      const int ex = (int)((u >> 23) & 255u) - 127;
      const float r = __uint_as_float((uint32_t)(127 - ex) << 23);
      p *= r;
      MUi += ex;
    }

    MU += (double)se;
    e_r = e_nxt;
    id_pref = id_nxt;
  }

  // epilogue: score[b][l] = (MU + lse_s(out_log2[l][s] + log2 p)) * ln2
  const float f = LOG2(p);
  const double MUt = MU + (double)MUi;
  for (int l = 0; l < NLABEL; ++l) {
    float y;
    if (PRE) {
      y = out2[l * NSTATE + s] + f;
    } else {
      const float v = outp[l * NSTATE + s] * LOG2E;
      const float lm = wave_max64(v);
      const float lsum = wave_sum64(EXP2(v - lm));
      y = v - lm - LOG2(lsum) + f;
    }
    const float m = wave_max64(y);
    const float ssum = wave_sum64(EXP2(y - m));
    if (s == 0) {
      const double sc = MUt + (double)m + (double)LOG2(ssum);
      score[b * NLABEL + l] = (float)(sc * LN2_D);
    }
  }
}

extern "C" void kernel_launch(void* const* d_in, const int* in_sizes, int n_in,
                              void* d_out, int out_size, void* d_ws, size_t ws_size,
                              hipStream_t stream) {
  const int* sents = (const int*)d_in[0];
  const int* length = (const int*)d_in[1];
  const float* emb = (const float*)d_in[2];
  const float* trans = (const float*)d_in[3];
  const float* outp = (const float*)d_in[4];
  float* score = (float*)d_out;

  const size_t emb2_bytes = (size_t)VOCAB * NSTATE * sizeof(float);
  const size_t W_off = emb2_bytes;
  const size_t out2_off = W_off + NSTATE * NSTATE * sizeof(float);
  const size_t need = out2_off + NLABEL * NSTATE * sizeof(float);

  if (ws_size >= need) {
    float* emb2 = (float*)d_ws;
    float* W = (float*)((char*)d_ws + W_off);
    float* out2 = (float*)((char*)d_ws + out2_off);
    prep_emb_k<<<VOCAB / 4, 256, 0, stream>>>(emb, emb2);
    prep_mats_k<<<NSTATE + NLABEL, 64, 0, stream>>>(trans, outp, W, out2);
    iohmm_fwd<true><<<BATCH, 64, 0, stream>>>(sents, length, emb, trans, outp,
                                              emb2, W, out2, score);
  } else {
    iohmm_fwd<false><<<BATCH, 64, 0, stream>>>(sents, length, emb, trans, outp,
                                               nullptr, nullptr, nullptr, score);
  }
}